// Round 5
// baseline (1047.204 us; speedup 1.0000x reference)
//
#include <hip/hip_runtime.h>
#include <cstdint>
#include <cstddef>

#define TGT  2048
#define BSZN 2
#define NH   16
#define HD   64
#define ED   1024
#define ROWS (TGT*BSZN)   // 4096
#define BHN  (BSZN*NH)    // 32

typedef __attribute__((ext_vector_type(8))) short short8;   // 8 bf16 (4 VGPRs)
typedef __attribute__((ext_vector_type(4))) float floatx4;  // MFMA C/D

__device__ inline unsigned short f2bf(float f) {            // RNE float->bf16
    unsigned u = __float_as_uint(f);
    u += 0x7FFFu + ((u >> 16) & 1u);
    return (unsigned short)(u >> 16);
}
__device__ inline float bf2f(unsigned short s) {
    return __uint_as_float(((unsigned)s) << 16);
}

// ---------------------------------------------------------------------------
// Mask prep: sniff encoding (int32 / byte / float) and expand to fp32 0/1.
// ---------------------------------------------------------------------------
__global__ __launch_bounds__(256) void prep_mask(const unsigned char* __restrict__ mraw,
                                                 float* __restrict__ maskf) {
    __shared__ int cf, cb;
    int tid = threadIdx.x;
    if (tid == 0) { cf = 0; cb = 0; }
    __syncthreads();
    int lf = 0, lb = 0;
    for (int i = tid; i < BSZN * TGT; i += 256) {
        unsigned char v = mraw[i];
        if ((i & 3) == 3 && v == 0x3F) lf++;
        if ((i & 3) != 0 && v != 0)    lb++;
    }
    if (lf) atomicAdd(&cf, lf);
    if (lb) atomicAdd(&cb, lb);
    __syncthreads();
    int fmt = (cf > 256) ? 2 : (cb > 0 ? 1 : 0);  // 2=float, 1=byte, 0=int32
    for (int i = tid; i < BSZN * TGT; i += 256) {
        bool on;
        if (fmt == 2)      on = ((const float*)mraw)[i] != 0.0f;
        else if (fmt == 1) on = (mraw[i] != 0);
        else               on = (mraw[4 * i] != 0);
        maskf[i] = on ? 1.0f : 0.0f;
    }
}

// ---------------------------------------------------------------------------
// fp32 -> (hi, lo) bf16 planes, 4 elems/thread.
// ---------------------------------------------------------------------------
__global__ __launch_bounds__(256) void convert_hilo(const float* __restrict__ src,
                                                    unsigned short* __restrict__ dh,
                                                    unsigned short* __restrict__ dl,
                                                    int n4) {
    int i = blockIdx.x * 256 + threadIdx.x;
    if (i >= n4) return;
    float4 v = ((const float4*)src)[i];
    ushort4 h, l;
    h.x = f2bf(v.x); l.x = f2bf(v.x - bf2f(h.x));
    h.y = f2bf(v.y); l.y = f2bf(v.y - bf2f(h.y));
    h.z = f2bf(v.z); l.z = f2bf(v.z - bf2f(h.z));
    h.w = f2bf(v.w); l.w = f2bf(v.w - bf2f(h.w));
    ((ushort4*)dh)[i] = h;
    ((ushort4*)dl)[i] = l;
}

// ---------------------------------------------------------------------------
// Split-bf16 NT GEMM: Y[m][n] = (sum_k A[m][k]*B[n][k] + bias[n]) * scale
// A,B given as hi/lo bf16 planes. Tile 128(M)x64(N), BK=64, 256 thr (4 waves).
// Wave w owns rows [w*32, w*32+32) via two 16-row MFMA granules.
// mode 0: fp32 -> Yf ; mode 1: bf16(hi only) -> Yb ; mode 2: vT transpose.
// MFMA 16x16x32 bf16: A[m=lane&15][k=quad*8+j]; C: col=lane&15, row=quad*4+reg.
// ---------------------------------------------------------------------------
__global__ __launch_bounds__(256) void gemm_split(
    const unsigned short* __restrict__ AH, const unsigned short* __restrict__ AL,
    const unsigned short* __restrict__ BH, const unsigned short* __restrict__ BL,
    const float* __restrict__ bias, float scale, int K,
    int mode, float* __restrict__ Yf, unsigned short* __restrict__ Yb, int ldy)
{
    // row pad to 72 (144 B, 16B-aligned, 36-bank stride -> <=2-way conflicts)
    __shared__ unsigned short Ahs[128][72];
    __shared__ unsigned short Als[128][72];
    __shared__ unsigned short Bhs[64][72];
    __shared__ unsigned short Bls[64][72];

    int tid = threadIdx.x;
    int w = tid >> 6, lane = tid & 63, lm = lane & 15, quad = lane >> 4;
    int m0 = blockIdx.y * 128, n0 = blockIdx.x * 64;

    floatx4 acc[2][4];
#pragma unroll
    for (int g = 0; g < 2; ++g)
#pragma unroll
        for (int j = 0; j < 4; ++j) acc[g][j] = (floatx4){0.f, 0.f, 0.f, 0.f};

    for (int kt = 0; kt < K; kt += 64) {
#pragma unroll
        for (int s = 0; s < 4; ++s) {            // A: 128 rows x 64 k per plane
            int idx = tid + s * 256;
            int r = idx >> 3, c8 = (idx & 7) * 8;
            *(short8*)&Ahs[r][c8] = *(const short8*)&AH[(size_t)(m0 + r) * ED + kt + c8];
            *(short8*)&Als[r][c8] = *(const short8*)&AL[(size_t)(m0 + r) * ED + kt + c8];
        }
#pragma unroll
        for (int s = 0; s < 2; ++s) {            // B: 64 rows x 64 k per plane
            int idx = tid + s * 256;
            int r = idx >> 3, c8 = (idx & 7) * 8;
            *(short8*)&Bhs[r][c8] = *(const short8*)&BH[(size_t)(n0 + r) * ED + kt + c8];
            *(short8*)&Bls[r][c8] = *(const short8*)&BL[(size_t)(n0 + r) * ED + kt + c8];
        }
        __syncthreads();
#pragma unroll
        for (int kk = 0; kk < 64; kk += 32) {
            short8 ah0 = *(const short8*)&Ahs[w * 32 + lm][kk + quad * 8];
            short8 al0 = *(const short8*)&Als[w * 32 + lm][kk + quad * 8];
            short8 ah1 = *(const short8*)&Ahs[w * 32 + 16 + lm][kk + quad * 8];
            short8 al1 = *(const short8*)&Als[w * 32 + 16 + lm][kk + quad * 8];
#pragma unroll
            for (int j = 0; j < 4; ++j) {
                short8 bh = *(const short8*)&Bhs[j * 16 + lm][kk + quad * 8];
                short8 bl = *(const short8*)&Bls[j * 16 + lm][kk + quad * 8];
                floatx4 t0 = acc[0][j];
                t0 = __builtin_amdgcn_mfma_f32_16x16x32_bf16(ah0, bl, t0, 0, 0, 0);
                t0 = __builtin_amdgcn_mfma_f32_16x16x32_bf16(al0, bh, t0, 0, 0, 0);
                t0 = __builtin_amdgcn_mfma_f32_16x16x32_bf16(ah0, bh, t0, 0, 0, 0);
                acc[0][j] = t0;
                floatx4 t1 = acc[1][j];
                t1 = __builtin_amdgcn_mfma_f32_16x16x32_bf16(ah1, bl, t1, 0, 0, 0);
                t1 = __builtin_amdgcn_mfma_f32_16x16x32_bf16(al1, bh, t1, 0, 0, 0);
                t1 = __builtin_amdgcn_mfma_f32_16x16x32_bf16(ah1, bh, t1, 0, 0, 0);
                acc[1][j] = t1;
            }
        }
        __syncthreads();
    }

    if (mode == 2) {
        // stage (val+bias) as bf16 into LDS, then write vT[bh][d][t] coalesced
        unsigned short (*Ct)[72] = Ahs;   // 128 x 64 needed; reuse A-hi plane
#pragma unroll
        for (int g = 0; g < 2; ++g)
#pragma unroll
            for (int j = 0; j < 4; ++j)
#pragma unroll
                for (int r = 0; r < 4; ++r) {
                    int row = w * 32 + g * 16 + quad * 4 + r;
                    int col = j * 16 + lm;
                    Ct[row][col] = f2bf(acc[g][j][r] + bias[n0 + col]);
                }
        __syncthreads();
        int h = n0 >> 6;
        int seg = tid >> 1, half = tid & 1;
        int bsel = seg >> 6, d = seg & 63;
        size_t base = ((size_t)((bsel * NH + h) * HD + d)) * TGT + (m0 >> 1) + half * 32;
#pragma unroll
        for (int grp = 0; grp < 4; ++grp) {
            short8 ov;
#pragma unroll
            for (int u = 0; u < 8; ++u) {
                int tl = half * 32 + grp * 8 + u;
                ov[u] = (short)Ct[tl * 2 + bsel][d];
            }
            *(short8*)&Yb[base + grp * 8] = ov;
        }
    } else {
#pragma unroll
        for (int g = 0; g < 2; ++g)
#pragma unroll
            for (int j = 0; j < 4; ++j)
#pragma unroll
                for (int r = 0; r < 4; ++r) {
                    int grow = m0 + w * 32 + g * 16 + quad * 4 + r;
                    int col = n0 + j * 16 + lm;
                    float val = (acc[g][j][r] + bias[col]) * scale;
                    if (mode == 0) Yf[(size_t)grow * ldy + col] = val;
                    else           Yb[(size_t)grow * ldy + col] = f2bf(val);
                }
    }
}

// ---------------------------------------------------------------------------
// Fused scores + mask + softmax + PV, max-residency shape.
// One wg = 128 threads = 2 waves = 16 q-rows x 2048 keys for one (b,h);
// wave w handles key-half [w*1024, w*1024+1024). Coupling between the pair:
//   - softmax denominators combined via tiny LDS exchange (commutative add)
//   - PV partial accumulators summed at the end (LDS, reusing P scratch).
// Grid = 4096 wgs -> 16 wgs/CU x 2 waves = 32 waves/CU under all residency
// caps (LDS ~4.9 KB/wg, VGPR<=64, wg-slots<=16).
// P scratch is bf16 (f2bf at production): halves LDS, A-frag read becomes a
// single ds_read_b128, no read-side cvt/pack.
// wout stores are plain (not NT): full-line L2 write-combining (NT partial
// 64B quad-writes amplified HBM writes 540->650 MB in rounds 2/4).
// Epilogue: context written directly as hi/lo bf16 planes (wave 0 only).
// ---------------------------------------------------------------------------
__global__ __launch_bounds__(128) void scores_pv_fused(
    const unsigned short* __restrict__ qH, const unsigned short* __restrict__ kH,
    const unsigned short* __restrict__ vT, const float* __restrict__ maskf,
    float* __restrict__ wout,
    unsigned short* __restrict__ ctxH, unsigned short* __restrict__ ctxL)
{
    __shared__ unsigned short ot[2][16][72];   // per-wave bf16 P scratch (4.6KB)
    __shared__ float rsx[2][4][4];             // per-wave partial denominators
    int tid = threadIdx.x;
    int w = tid >> 6, lane = tid & 63, lm = lane & 15, quad = lane >> 4;

    // XCD-aware remap: slot -> (bh, t-chunk); 4096 wgs, 8 XCDs, bijective.
    int slot = blockIdx.x;
    int xcd = slot & 7, rr = slot >> 3;        // rr in [0,512)
    int bh = xcd * 4 + (rr >> 7);              // [0,32)
    int t0 = (rr & 127) * 16;                  // [0,2048) step 16
    int bsel = bh >> 4, h = bh & 15;
    int k0 = w * (TGT / 2);                    // this wave's keys [k0, k0+1024)

    const unsigned short* qrow =
        qH + ((size_t)((t0 + lm) * BSZN + bsel)) * ED + h * HD + quad * 8;
    short8 a0 = *(const short8*)qrow;
    short8 a1 = *(const short8*)(qrow + 32);

    const float* mrow = maskf + bsel * TGT;
    float* wbh = wout + (size_t)bh * TGT * TGT;
    const unsigned short* vb = vT + (size_t)bh * HD * TGT;

    // ---- pass 1: partial row sums (x2 unroll, independent accumulators) ----
    float rs[4] = {0.f, 0.f, 0.f, 0.f};
    for (int s0 = k0; s0 < k0 + TGT / 2; s0 += 32) {
        int keyA = s0 + lm, keyB = s0 + 16 + lm;
        const unsigned short* krA = kH + ((size_t)(keyA * BSZN + bsel)) * ED + h * HD + quad * 8;
        const unsigned short* krB = kH + ((size_t)(keyB * BSZN + bsel)) * ED + h * HD + quad * 8;
        short8 b0A = *(const short8*)krA;
        short8 b1A = *(const short8*)(krA + 32);
        short8 b0B = *(const short8*)krB;
        short8 b1B = *(const short8*)(krB + 32);
        float mkA = mrow[keyA], mkB = mrow[keyB];
        floatx4 sA = (floatx4){0.f, 0.f, 0.f, 0.f};
        floatx4 sB = (floatx4){0.f, 0.f, 0.f, 0.f};
        sA = __builtin_amdgcn_mfma_f32_16x16x32_bf16(a0, b0A, sA, 0, 0, 0);
        sB = __builtin_amdgcn_mfma_f32_16x16x32_bf16(a0, b0B, sB, 0, 0, 0);
        sA = __builtin_amdgcn_mfma_f32_16x16x32_bf16(a1, b1A, sA, 0, 0, 0);
        sB = __builtin_amdgcn_mfma_f32_16x16x32_bf16(a1, b1B, sB, 0, 0, 0);
#pragma unroll
        for (int r = 0; r < 4; ++r) {
            rs[r] += (mkA != 0.f) ? 0.f : __expf(sA[r]);
            rs[r] += (mkB != 0.f) ? 0.f : __expf(sB[r]);
        }
    }
#pragma unroll
    for (int off = 1; off < 16; off <<= 1) {
#pragma unroll
        for (int r = 0; r < 4; ++r) rs[r] += __shfl_xor(rs[r], off, 64);
    }
    // combine the two key-half partials (fp add is commutative -> deterministic)
    if (lm == 0) {
#pragma unroll
        for (int r = 0; r < 4; ++r) rsx[w][quad][r] = rs[r];
    }
    __syncthreads();
    float rinv[4];
#pragma unroll
    for (int r = 0; r < 4; ++r) rinv[r] = 1.0f / (rs[r] + rsx[w ^ 1][quad][r]);

    // ---- pass 2: weights from regs + PV from private bf16 LDS scratch ----
    floatx4 acc[4];
#pragma unroll
    for (int j = 0; j < 4; ++j) acc[j] = (floatx4){0.f, 0.f, 0.f, 0.f};

    float* wrow = wbh + (size_t)(t0 + quad * 4) * TGT;   // rows quad*4+r

    for (int c0 = k0; c0 < k0 + TGT / 2; c0 += 64) {
#pragma unroll
        for (int sub = 0; sub < 4; ++sub) {
            int key = c0 + sub * 16 + lm;
            const unsigned short* kr = kH + ((size_t)(key * BSZN + bsel)) * ED + h * HD + quad * 8;
            short8 b0 = *(const short8*)kr;
            short8 b1 = *(const short8*)(kr + 32);
            floatx4 s = (floatx4){0.f, 0.f, 0.f, 0.f};
            s = __builtin_amdgcn_mfma_f32_16x16x32_bf16(a0, b0, s, 0, 0, 0);
            s = __builtin_amdgcn_mfma_f32_16x16x32_bf16(a1, b1, s, 0, 0, 0);
            float mk = mrow[key];
#pragma unroll
            for (int r = 0; r < 4; ++r) {
                float e = (mk != 0.f) ? 0.f : __expf(s[r]);
                float v = e * rinv[r];
                wrow[(size_t)r * TGT + key] = v;
                ot[w][quad * 4 + r][sub * 16 + lm] = f2bf(v);
            }
        }
        // PV: A-frag = single b128 read of this wave's own rows (same-wave LDS)
#pragma unroll
        for (int kk = 0; kk < 64; kk += 32) {
            short8 af = *(const short8*)&ot[w][lm][kk + quad * 8];
#pragma unroll
            for (int j = 0; j < 4; ++j) {
                short8 bf = *(const short8*)&vb[(size_t)(j * 16 + lm) * TGT + c0 + kk + quad * 8];
                acc[j] = __builtin_amdgcn_mfma_f32_16x16x32_bf16(af, bf, acc[j], 0, 0, 0);
            }
        }
    }

    // ---- combine PV partials across the wave pair (reuse ot as f32 scratch) --
    float* cmb = (float*)&ot[0][0][0];   // 1152 floats >= 16*68
    __syncthreads();                     // both waves done with their ot region
    if (w == 1) {
#pragma unroll
        for (int j = 0; j < 4; ++j)
#pragma unroll
            for (int r = 0; r < 4; ++r)
                cmb[(quad * 4 + r) * 68 + j * 16 + lm] = acc[j][r];
    }
    __syncthreads();
    if (w == 0) {
#pragma unroll
        for (int j = 0; j < 4; ++j)
#pragma unroll
            for (int r = 0; r < 4; ++r)
                acc[j][r] += cmb[(quad * 4 + r) * 68 + j * 16 + lm];

        // ---- epilogue: context -> hi/lo bf16 planes directly ----
#pragma unroll
        for (int j = 0; j < 4; ++j)
#pragma unroll
            for (int r = 0; r < 4; ++r) {
                int t = t0 + quad * 4 + r;
                int d = j * 16 + lm;
                size_t idx = (size_t)(t * BSZN + bsel) * ED + h * HD + d;
                float val = acc[j][r];
                unsigned short hi = f2bf(val);
                ctxH[idx] = hi;
                ctxL[idx] = f2bf(val - bf2f(hi));
            }
    }
}

// ---------------------------------------------------------------------------
extern "C" void kernel_launch(void* const* d_in, const int* in_sizes, int n_in,
                              void* d_out, int out_size, void* d_ws, size_t ws_size,
                              hipStream_t stream) {
    const float* query = (const float*)d_in[0];
    const unsigned char* mraw = (const unsigned char*)d_in[1];
    const float* qw = (const float*)d_in[2];
    const float* qb = (const float*)d_in[3];
    const float* kw = (const float*)d_in[4];
    const float* kb = (const float*)d_in[5];
    const float* vw = (const float*)d_in[6];
    const float* vb = (const float*)d_in[7];
    const float* ow = (const float*)d_in[8];
    const float* ob = (const float*)d_in[9];

    float* out  = (float*)d_out;                     // attn: ROWS*ED fp32
    float* wout = out + (size_t)ROWS * ED;           // weights: 32*2048*2048 fp32

    // ws layout (bytes), total 44.06 MB (< proven 48 MB budget):
    char* wsb = (char*)d_ws;
    float* maskf           = (float*)(wsb);                       // 16 KB
    unsigned short* qryH   = (unsigned short*)(wsb + 65536);      // 8 MB
    unsigned short* qryL   = qryH + (size_t)ROWS * ED;            // 8 MB
    unsigned short* wWH    = qryL + (size_t)ROWS * ED;            // 2 MB (rotating)
    unsigned short* wWL    = wWH + (size_t)ED * ED;               // 2 MB (rotating)
    unsigned short* qHp    = wWL + (size_t)ED * ED;               // 8 MB
    unsigned short* kHp    = qHp + (size_t)ROWS * ED;             // 8 MB
    unsigned short* vT     = kHp + (size_t)ROWS * ED;             // 8 MB
    // ctx hi/lo planes alias qryH/qryL (dead after the 3 projection GEMMs).
    // NOTE: must NOT alias qHp/kHp — scores_pv_fused reads those while writing ctx.
    unsigned short* ctxH   = qryH;
    unsigned short* ctxL   = qryL;

    dim3 blk(256);
    dim3 ggrid(ED / 64, ROWS / 128);   // (16, 32)

    prep_mask<<<1, blk, 0, stream>>>(mraw, maskf);
    convert_hilo<<<(ROWS * ED / 4 + 255) / 256, blk, 0, stream>>>(query, qryH, qryL, ROWS * ED / 4);

    // Q projection -> bf16 plane, scale 0.125 (bias before scale)
    convert_hilo<<<(ED * ED / 4 + 255) / 256, blk, 0, stream>>>(qw, wWH, wWL, ED * ED / 4);
    gemm_split<<<ggrid, blk, 0, stream>>>(qryH, qryL, wWH, wWL, qb, 0.125f, ED, 1, nullptr, qHp, ED);
    // K projection -> bf16 plane
    convert_hilo<<<(ED * ED / 4 + 255) / 256, blk, 0, stream>>>(kw, wWH, wWL, ED * ED / 4);
    gemm_split<<<ggrid, blk, 0, stream>>>(qryH, qryL, wWH, wWL, kb, 1.0f, ED, 1, nullptr, kHp, ED);
    // V projection -> vT bf16 [bh][d][t]
    convert_hilo<<<(ED * ED / 4 + 255) / 256, blk, 0, stream>>>(vw, wWH, wWL, ED * ED / 4);
    gemm_split<<<ggrid, blk, 0, stream>>>(qryH, qryL, wWH, wWL, vb, 1.0f, ED, 2, nullptr, vT, ED);

    // fused scores + mask + softmax + PV (4096 wgs x 128 thr: 32 bh x 128 row-chunks)
    scores_pv_fused<<<dim3(BHN * (TGT / 16)), dim3(128), 0, stream>>>(qHp, kHp, vT, maskf, wout, ctxH, ctxL);

    // out projection: ctx planes -> fp32 out
    convert_hilo<<<(ED * ED / 4 + 255) / 256, blk, 0, stream>>>(ow, wWH, wWL, ED * ED / 4);
    gemm_split<<<ggrid, blk, 0, stream>>>(ctxH, ctxL, wWH, wWL, ob, 1.0f, ED, 0, out, nullptr, ED);
}

// Round 6
// 844.501 us; speedup vs baseline: 1.2400x; 1.2400x over previous
//
#include <hip/hip_runtime.h>
#include <cstdint>
#include <cstddef>

#define TGT  2048
#define BSZN 2
#define NH   16
#define HD   64
#define ED   1024
#define ROWS (TGT*BSZN)   // 4096
#define BHN  (BSZN*NH)    // 32

typedef __attribute__((ext_vector_type(8))) short short8;   // 8 bf16 (4 VGPRs)
typedef __attribute__((ext_vector_type(4))) float floatx4;  // MFMA C/D

__device__ inline unsigned short f2bf(float f) {            // RNE float->bf16
    unsigned u = __float_as_uint(f);
    u += 0x7FFFu + ((u >> 16) & 1u);
    return (unsigned short)(u >> 16);
}
__device__ inline float bf2f(unsigned short s) {
    return __uint_as_float(((unsigned)s) << 16);
}

// ---------------------------------------------------------------------------
// Mask prep: sniff encoding (int32 / byte / float) and expand to fp32 0/1.
// ---------------------------------------------------------------------------
__global__ __launch_bounds__(256) void prep_mask(const unsigned char* __restrict__ mraw,
                                                 float* __restrict__ maskf) {
    __shared__ int cf, cb;
    int tid = threadIdx.x;
    if (tid == 0) { cf = 0; cb = 0; }
    __syncthreads();
    int lf = 0, lb = 0;
    for (int i = tid; i < BSZN * TGT; i += 256) {
        unsigned char v = mraw[i];
        if ((i & 3) == 3 && v == 0x3F) lf++;
        if ((i & 3) != 0 && v != 0)    lb++;
    }
    if (lf) atomicAdd(&cf, lf);
    if (lb) atomicAdd(&cb, lb);
    __syncthreads();
    int fmt = (cf > 256) ? 2 : (cb > 0 ? 1 : 0);  // 2=float, 1=byte, 0=int32
    for (int i = tid; i < BSZN * TGT; i += 256) {
        bool on;
        if (fmt == 2)      on = ((const float*)mraw)[i] != 0.0f;
        else if (fmt == 1) on = (mraw[i] != 0);
        else               on = (mraw[4 * i] != 0);
        maskf[i] = on ? 1.0f : 0.0f;
    }
}

// ---------------------------------------------------------------------------
// fp32 -> (hi, lo) bf16 planes, 4 elems/thread.
// ---------------------------------------------------------------------------
__global__ __launch_bounds__(256) void convert_hilo(const float* __restrict__ src,
                                                    unsigned short* __restrict__ dh,
                                                    unsigned short* __restrict__ dl,
                                                    int n4) {
    int i = blockIdx.x * 256 + threadIdx.x;
    if (i >= n4) return;
    float4 v = ((const float4*)src)[i];
    ushort4 h, l;
    h.x = f2bf(v.x); l.x = f2bf(v.x - bf2f(h.x));
    h.y = f2bf(v.y); l.y = f2bf(v.y - bf2f(h.y));
    h.z = f2bf(v.z); l.z = f2bf(v.z - bf2f(h.z));
    h.w = f2bf(v.w); l.w = f2bf(v.w - bf2f(h.w));
    ((ushort4*)dh)[i] = h;
    ((ushort4*)dl)[i] = l;
}

// ---------------------------------------------------------------------------
// Split-bf16 NT GEMM: Y[m][n] = (sum_k A[m][k]*B[n][k] + bias[n]) * scale
// A,B given as hi/lo bf16 planes. Tile 128(M)x64(N), BK=64, 256 thr (4 waves).
// mode 0: fp32 -> Yf
// mode 1: bf16(hi) -> Yb row-major [grow][col]            (Q projection)
// mode 2: bf16 V in PV-fragment-tiled layout:             (V projection)
//         vTt[bh][key>>5][d>>4][(key>>3)&3][ (d&15)*8 + (key&7) ]
//         (so a PV B-frag load is lane-contiguous: base + lane*8)
// mode 3: bf16 K in QK-fragment-tiled layout:             (K projection)
//         kT[bh][key>>4][d>>5][(d>>3)&3][ (key&15)*8 + (d&7) ]
//         (so a QK B-frag load is lane-contiguous: c*1024 + lane*8, +512 for b1)
// MFMA 16x16x32 bf16: A[m=lane&15][k=quad*8+j]; C: col=lane&15, row=quad*4+reg.
// ---------------------------------------------------------------------------
__global__ __launch_bounds__(256) void gemm_split(
    const unsigned short* __restrict__ AH, const unsigned short* __restrict__ AL,
    const unsigned short* __restrict__ BH, const unsigned short* __restrict__ BL,
    const float* __restrict__ bias, float scale, int K,
    int mode, float* __restrict__ Yf, unsigned short* __restrict__ Yb, int ldy)
{
    // row pad to 72 (144 B, 16B-aligned, 36-bank stride -> <=2-way conflicts)
    __shared__ unsigned short Ahs[128][72];
    __shared__ unsigned short Als[128][72];
    __shared__ unsigned short Bhs[64][72];
    __shared__ unsigned short Bls[64][72];

    int tid = threadIdx.x;
    int w = tid >> 6, lane = tid & 63, lm = lane & 15, quad = lane >> 4;
    int m0 = blockIdx.y * 128, n0 = blockIdx.x * 64;

    floatx4 acc[2][4];
#pragma unroll
    for (int g = 0; g < 2; ++g)
#pragma unroll
        for (int j = 0; j < 4; ++j) acc[g][j] = (floatx4){0.f, 0.f, 0.f, 0.f};

    for (int kt = 0; kt < K; kt += 64) {
#pragma unroll
        for (int s = 0; s < 4; ++s) {            // A: 128 rows x 64 k per plane
            int idx = tid + s * 256;
            int r = idx >> 3, c8 = (idx & 7) * 8;
            *(short8*)&Ahs[r][c8] = *(const short8*)&AH[(size_t)(m0 + r) * ED + kt + c8];
            *(short8*)&Als[r][c8] = *(const short8*)&AL[(size_t)(m0 + r) * ED + kt + c8];
        }
#pragma unroll
        for (int s = 0; s < 2; ++s) {            // B: 64 rows x 64 k per plane
            int idx = tid + s * 256;
            int r = idx >> 3, c8 = (idx & 7) * 8;
            *(short8*)&Bhs[r][c8] = *(const short8*)&BH[(size_t)(n0 + r) * ED + kt + c8];
            *(short8*)&Bls[r][c8] = *(const short8*)&BL[(size_t)(n0 + r) * ED + kt + c8];
        }
        __syncthreads();
#pragma unroll
        for (int kk = 0; kk < 64; kk += 32) {
            short8 ah0 = *(const short8*)&Ahs[w * 32 + lm][kk + quad * 8];
            short8 al0 = *(const short8*)&Als[w * 32 + lm][kk + quad * 8];
            short8 ah1 = *(const short8*)&Ahs[w * 32 + 16 + lm][kk + quad * 8];
            short8 al1 = *(const short8*)&Als[w * 32 + 16 + lm][kk + quad * 8];
#pragma unroll
            for (int j = 0; j < 4; ++j) {
                short8 bh = *(const short8*)&Bhs[j * 16 + lm][kk + quad * 8];
                short8 bl = *(const short8*)&Bls[j * 16 + lm][kk + quad * 8];
                floatx4 t0 = acc[0][j];
                t0 = __builtin_amdgcn_mfma_f32_16x16x32_bf16(ah0, bl, t0, 0, 0, 0);
                t0 = __builtin_amdgcn_mfma_f32_16x16x32_bf16(al0, bh, t0, 0, 0, 0);
                t0 = __builtin_amdgcn_mfma_f32_16x16x32_bf16(ah0, bh, t0, 0, 0, 0);
                acc[0][j] = t0;
                floatx4 t1 = acc[1][j];
                t1 = __builtin_amdgcn_mfma_f32_16x16x32_bf16(ah1, bl, t1, 0, 0, 0);
                t1 = __builtin_amdgcn_mfma_f32_16x16x32_bf16(al1, bh, t1, 0, 0, 0);
                t1 = __builtin_amdgcn_mfma_f32_16x16x32_bf16(ah1, bh, t1, 0, 0, 0);
                acc[1][j] = t1;
            }
        }
        __syncthreads();
    }

    if (mode == 2) {
        // stage (val+bias) as bf16 into LDS, then write V fragment-tiled
        unsigned short (*Ct)[72] = Ahs;   // 128 x 64 needed; reuse A-hi plane
#pragma unroll
        for (int g = 0; g < 2; ++g)
#pragma unroll
            for (int j = 0; j < 4; ++j)
#pragma unroll
                for (int r = 0; r < 4; ++r) {
                    int row = w * 32 + g * 16 + quad * 4 + r;
                    int col = j * 16 + lm;
                    Ct[row][col] = f2bf(acc[g][j][r] + bias[n0 + col]);
                }
        __syncthreads();
        int hh = n0 >> 6;
        int seg = tid >> 1, hf = tid & 1;
        int bsel2 = seg >> 6, dd = seg & 63;
        int bhx = bsel2 * 16 + hh;
        size_t bhbase = (size_t)bhx * HD * TGT;
#pragma unroll
        for (int grp = 0; grp < 4; ++grp) {
            int key0 = (m0 >> 1) + hf * 32 + grp * 8;
            size_t base = bhbase + (size_t)(key0 >> 5) * 2048 + (size_t)(dd >> 4) * 512
                        + (size_t)((key0 >> 3) & 3) * 128 + (size_t)(dd & 15) * 8;
            short8 ov;
#pragma unroll
            for (int u = 0; u < 8; ++u) {
                int tl = hf * 32 + grp * 8 + u;
                ov[u] = (short)Ct[tl * 2 + bsel2][dd];
            }
            *(short8*)&Yb[base] = ov;
        }
    } else if (mode == 3) {
        // K fragment-tiled store
        int hh = n0 >> 6;
#pragma unroll
        for (int g = 0; g < 2; ++g)
#pragma unroll
            for (int j = 0; j < 4; ++j)
#pragma unroll
                for (int r = 0; r < 4; ++r) {
                    int grow = m0 + w * 32 + g * 16 + quad * 4 + r;
                    int col = n0 + j * 16 + lm;
                    int t = grow >> 1, b = grow & 1;
                    int d = col & 63;
                    int bhx = b * 16 + hh;
                    float val = (acc[g][j][r] + bias[col]) * scale;
                    size_t a = (size_t)bhx * TGT * HD + (size_t)(t >> 4) * 1024
                             + (size_t)(d >> 5) * 512 + (size_t)((d >> 3) & 3) * 128
                             + (size_t)(t & 15) * 8 + (size_t)(d & 7);
                    Yb[a] = f2bf(val);
                }
    } else {
#pragma unroll
        for (int g = 0; g < 2; ++g)
#pragma unroll
            for (int j = 0; j < 4; ++j)
#pragma unroll
                for (int r = 0; r < 4; ++r) {
                    int grow = m0 + w * 32 + g * 16 + quad * 4 + r;
                    int col = n0 + j * 16 + lm;
                    float val = (acc[g][j][r] + bias[col]) * scale;
                    if (mode == 0) Yf[(size_t)grow * ldy + col] = val;
                    else           Yb[(size_t)grow * ldy + col] = f2bf(val);
                }
    }
}

// ---------------------------------------------------------------------------
// Fused scores + mask + softmax + PV (round-4 shape + fragment-tiled loads).
// One wg = 32 q-rows x 2048 keys for one (b,h); 4 waves = 2 row-groups x
// 2 key-halves; each wave 16 rows x 1024 keys. Coupling: denominator
// exchange (LDS + barrier) and PV-partial combine at the end.
// ALL K and V fragment loads are lane-contiguous 1KB wave-bursts thanks to
// the tiled layouts produced by gemm_split modes 2/3 (was: 16-line scatter).
// P scratch is bf16 (single ds_read_b128 A-frag, no read-side cvt).
// wout stores plain (NT partial-line stores amplified HBM writes, r2/r4).
// ---------------------------------------------------------------------------
__global__ __launch_bounds__(256) void scores_pv_fused(
    const unsigned short* __restrict__ qH, const unsigned short* __restrict__ kT,
    const unsigned short* __restrict__ vTt, const float* __restrict__ maskf,
    float* __restrict__ wout,
    unsigned short* __restrict__ ctxH, unsigned short* __restrict__ ctxL)
{
    __shared__ unsigned short ot[4][16][72];   // per-wave bf16 P scratch
    __shared__ float rsx[4][4][4];             // per-wave partial denominators
    int tid = threadIdx.x;
    int w = tid >> 6, lane = tid & 63, lm = lane & 15, quad = lane >> 4;
    int rg = w >> 1, half = w & 1;             // row-group, key-half

    // XCD-aware remap: slot -> (bh, t-chunk); 2048 wgs, 8 XCDs, bijective.
    int slot = blockIdx.x;
    int xcd = slot & 7, rr = slot >> 3;
    int bh = xcd * 4 + (rr >> 6);
    int t0 = (rr & 63) * 32;
    int bsel = bh >> 4, h = bh & 15;
    int k0 = half * (TGT / 2);                 // this wave's keys [k0, k0+1024)

    const unsigned short* qrow =
        qH + ((size_t)((t0 + rg * 16 + lm) * BSZN + bsel)) * ED + h * HD + quad * 8;
    short8 a0 = *(const short8*)qrow;
    short8 a1 = *(const short8*)(qrow + 32);

    const unsigned short* kbh = kT + (size_t)bh * TGT * HD;
    const unsigned short* vbh = vTt + (size_t)bh * HD * TGT;
    const float* mrow = maskf + bsel * TGT;
    float* wbh = wout + (size_t)bh * TGT * TGT;

    // ---- pass 1: partial row sums (x2 unroll, coalesced tiled K loads) ----
    float rs[4] = {0.f, 0.f, 0.f, 0.f};
    for (int s0 = k0; s0 < k0 + TGT / 2; s0 += 32) {
        int cA = s0 >> 4;
        const unsigned short* pA = kbh + (size_t)cA * 1024 + lane * 8;
        const unsigned short* pB = pA + 1024;
        short8 b0A = *(const short8*)pA;
        short8 b1A = *(const short8*)(pA + 512);
        short8 b0B = *(const short8*)pB;
        short8 b1B = *(const short8*)(pB + 512);
        float mkA = mrow[s0 + lm], mkB = mrow[s0 + 16 + lm];
        floatx4 sA = (floatx4){0.f, 0.f, 0.f, 0.f};
        floatx4 sB = (floatx4){0.f, 0.f, 0.f, 0.f};
        sA = __builtin_amdgcn_mfma_f32_16x16x32_bf16(a0, b0A, sA, 0, 0, 0);
        sB = __builtin_amdgcn_mfma_f32_16x16x32_bf16(a0, b0B, sB, 0, 0, 0);
        sA = __builtin_amdgcn_mfma_f32_16x16x32_bf16(a1, b1A, sA, 0, 0, 0);
        sB = __builtin_amdgcn_mfma_f32_16x16x32_bf16(a1, b1B, sB, 0, 0, 0);
#pragma unroll
        for (int r = 0; r < 4; ++r) {
            rs[r] += (mkA != 0.f) ? 0.f : __expf(sA[r]);
            rs[r] += (mkB != 0.f) ? 0.f : __expf(sB[r]);
        }
    }
#pragma unroll
    for (int off = 1; off < 16; off <<= 1) {
#pragma unroll
        for (int r = 0; r < 4; ++r) rs[r] += __shfl_xor(rs[r], off, 64);
    }
    // combine the two key-half partials (fp add is commutative -> deterministic)
    if (lm == 0) {
#pragma unroll
        for (int r = 0; r < 4; ++r) rsx[w][quad][r] = rs[r];
    }
    __syncthreads();
    float rinv[4];
#pragma unroll
    for (int r = 0; r < 4; ++r) rinv[r] = 1.0f / (rs[r] + rsx[w ^ 1][quad][r]);

    // ---- pass 2: weights from regs + PV via bf16 LDS scratch, no barriers ----
    floatx4 acc[4];
#pragma unroll
    for (int j = 0; j < 4; ++j) acc[j] = (floatx4){0.f, 0.f, 0.f, 0.f};

    float* wrow = wbh + (size_t)(t0 + rg * 16 + quad * 4) * TGT;  // rows quad*4+r

    for (int c0 = k0; c0 < k0 + TGT / 2; c0 += 64) {
#pragma unroll
        for (int sub = 0; sub < 4; ++sub) {
            int c = (c0 >> 4) + sub;
            const unsigned short* p = kbh + (size_t)c * 1024 + lane * 8;
            short8 b0 = *(const short8*)p;
            short8 b1 = *(const short8*)(p + 512);
            int key = c0 + sub * 16 + lm;
            floatx4 s = (floatx4){0.f, 0.f, 0.f, 0.f};
            s = __builtin_amdgcn_mfma_f32_16x16x32_bf16(a0, b0, s, 0, 0, 0);
            s = __builtin_amdgcn_mfma_f32_16x16x32_bf16(a1, b1, s, 0, 0, 0);
            float mk = mrow[key];
#pragma unroll
            for (int r = 0; r < 4; ++r) {
                float e = (mk != 0.f) ? 0.f : __expf(s[r]);
                float v = e * rinv[r];
                wrow[(size_t)r * TGT + key] = v;
                ot[w][quad * 4 + r][sub * 16 + lm] = f2bf(v);
            }
        }
        // PV: A-frag single b128 from own rows; B-frag coalesced tiled V load
#pragma unroll
        for (int kk = 0; kk < 64; kk += 32) {
            short8 af = *(const short8*)&ot[w][lm][kk + quad * 8];
            size_t vbase = (size_t)((c0 + kk) >> 5) * 2048 + lane * 8;
#pragma unroll
            for (int j = 0; j < 4; ++j) {
                short8 bf = *(const short8*)&vbh[vbase + (size_t)j * 512];
                acc[j] = __builtin_amdgcn_mfma_f32_16x16x32_bf16(af, bf, acc[j], 0, 0, 0);
            }
        }
    }

    // ---- combine PV partials across the key-half pair ----
    // reuse the pair's two contiguous ot regions as fp32 scratch (2*2304B >= 16*68*4B)
    float* cmb = (float*)&ot[rg * 2][0][0];
    __syncthreads();                 // both waves done reading their ot scratch
    if (half) {
#pragma unroll
        for (int j = 0; j < 4; ++j)
#pragma unroll
            for (int r = 0; r < 4; ++r)
                cmb[(quad * 4 + r) * 68 + j * 16 + lm] = acc[j][r];
    }
    __syncthreads();
    if (!half) {
#pragma unroll
        for (int j = 0; j < 4; ++j)
#pragma unroll
            for (int r = 0; r < 4; ++r)
                acc[j][r] += cmb[(quad * 4 + r) * 68 + j * 16 + lm];

        // ---- epilogue: context -> hi/lo bf16 planes directly ----
#pragma unroll
        for (int j = 0; j < 4; ++j)
#pragma unroll
            for (int r = 0; r < 4; ++r) {
                int t = t0 + rg * 16 + quad * 4 + r;
                int d = j * 16 + lm;
                size_t idx = (size_t)(t * BSZN + bsel) * ED + h * HD + d;
                float val = acc[j][r];
                unsigned short hi = f2bf(val);
                ctxH[idx] = hi;
                ctxL[idx] = f2bf(val - bf2f(hi));
            }
    }
}

// ---------------------------------------------------------------------------
extern "C" void kernel_launch(void* const* d_in, const int* in_sizes, int n_in,
                              void* d_out, int out_size, void* d_ws, size_t ws_size,
                              hipStream_t stream) {
    const float* query = (const float*)d_in[0];
    const unsigned char* mraw = (const unsigned char*)d_in[1];
    const float* qw = (const float*)d_in[2];
    const float* qb = (const float*)d_in[3];
    const float* kw = (const float*)d_in[4];
    const float* kb = (const float*)d_in[5];
    const float* vw = (const float*)d_in[6];
    const float* vb = (const float*)d_in[7];
    const float* ow = (const float*)d_in[8];
    const float* ob = (const float*)d_in[9];

    float* out  = (float*)d_out;                     // attn: ROWS*ED fp32
    float* wout = out + (size_t)ROWS * ED;           // weights: 32*2048*2048 fp32

    // ws layout (bytes), total 44.06 MB (< proven 48 MB budget):
    char* wsb = (char*)d_ws;
    float* maskf           = (float*)(wsb);                       // 16 KB
    unsigned short* qryH   = (unsigned short*)(wsb + 65536);      // 8 MB
    unsigned short* qryL   = qryH + (size_t)ROWS * ED;            // 8 MB
    unsigned short* wWH    = qryL + (size_t)ROWS * ED;            // 2 MB (rotating)
    unsigned short* wWL    = wWH + (size_t)ED * ED;               // 2 MB (rotating)
    unsigned short* qHp    = wWL + (size_t)ED * ED;               // 8 MB
    unsigned short* kTt    = qHp + (size_t)ROWS * ED;             // 8 MB (K tiled)
    unsigned short* vTt    = kTt + (size_t)ROWS * ED;             // 8 MB (V tiled)
    // ctx hi/lo planes alias qryH/qryL (dead after the 3 projection GEMMs).
    // NOTE: must NOT alias qHp/kTt — scores_pv_fused reads those while writing ctx.
    unsigned short* ctxH   = qryH;
    unsigned short* ctxL   = qryL;

    dim3 blk(256);
    dim3 ggrid(ED / 64, ROWS / 128);   // (16, 32)

    prep_mask<<<1, blk, 0, stream>>>(mraw, maskf);
    convert_hilo<<<(ROWS * ED / 4 + 255) / 256, blk, 0, stream>>>(query, qryH, qryL, ROWS * ED / 4);

    // Q projection -> bf16 row-major plane, scale 0.125 (bias before scale)
    convert_hilo<<<(ED * ED / 4 + 255) / 256, blk, 0, stream>>>(qw, wWH, wWL, ED * ED / 4);
    gemm_split<<<ggrid, blk, 0, stream>>>(qryH, qryL, wWH, wWL, qb, 0.125f, ED, 1, nullptr, qHp, ED);
    // K projection -> fragment-tiled bf16
    convert_hilo<<<(ED * ED / 4 + 255) / 256, blk, 0, stream>>>(kw, wWH, wWL, ED * ED / 4);
    gemm_split<<<ggrid, blk, 0, stream>>>(qryH, qryL, wWH, wWL, kb, 1.0f, ED, 3, nullptr, kTt, ED);
    // V projection -> fragment-tiled bf16
    convert_hilo<<<(ED * ED / 4 + 255) / 256, blk, 0, stream>>>(vw, wWH, wWL, ED * ED / 4);
    gemm_split<<<ggrid, blk, 0, stream>>>(qryH, qryL, wWH, wWL, vb, 1.0f, ED, 2, nullptr, vTt, ED);

    // fused scores + mask + softmax + PV (2048 wgs: 32 bh x 64 row-chunks)
    scores_pv_fused<<<dim3(BHN * (TGT / 32)), blk, 0, stream>>>(qHp, kTt, vTt, maskf, wout, ctxH, ctxL);

    // out projection: ctx planes -> fp32 out
    convert_hilo<<<(ED * ED / 4 + 255) / 256, blk, 0, stream>>>(ow, wWH, wWL, ED * ED / 4);
    gemm_split<<<ggrid, blk, 0, stream>>>(ctxH, ctxL, wWH, wWL, ob, 1.0f, ED, 0, out, nullptr, ED);
}